// Round 3
// baseline (187.922 us; speedup 1.0000x reference)
//
#include <hip/hip_runtime.h>
#include <hip/hip_bf16.h>

// DendriticLayerSiLU: out = silu(softmax-gated template proj) * (x @ W^T)
// N=4096 tokens, K=2048, H=1024, 32 windows of 64.
// Round 3: 4-deep LDS pipeline (160 KB), counted vmcnt + raw s_barrier
// (T3+T4), setprio around MFMA (T5). Prepass fused into one launch.

typedef __attribute__((ext_vector_type(8))) short short8;
typedef __attribute__((ext_vector_type(4))) float f32x4;

#define N_TOK 4096
#define K_DIM 2048
#define H_DIM 1024
#define BM 128
#define BH 128
#define BK 32
#define LDSZ (BM * BK)

#define X_ELEMS (N_TOK * K_DIM)   // 8388608
#define W_ELEMS (H_DIM * K_DIM)   // 2097152
#define WS_NEED ((size_t)(2 * X_ELEMS + 3 * W_ELEMS) * 2)  // 46,137,344 B

#define XB (X_ELEMS / 8 / 256)    // 4096 prepass blocks for X
#define WB (W_ELEMS / 8 / 256)    // 1024 for W, 1024 for T

__device__ __forceinline__ unsigned short f2bf(float f) {
    unsigned int u = __float_as_uint(f);
    u += 0x7FFFu + ((u >> 16) & 1u);    // round-to-nearest-even
    return (unsigned short)(u >> 16);
}
__device__ __forceinline__ float bf2f(unsigned short h) {
    return __uint_as_float(((unsigned int)h) << 16);
}

__device__ __forceinline__ void cvt_split(f32x4 a, f32x4 b, short8& vh, short8& vl) {
#pragma unroll
    for (int i = 0; i < 4; ++i) {
        float f = a[i];
        unsigned short h = f2bf(f);
        vh[i] = (short)h;
        vl[i] = (short)f2bf(f - bf2f(h));
    }
#pragma unroll
    for (int i = 0; i < 4; ++i) {
        float f = b[i];
        unsigned short h = f2bf(f);
        vh[i + 4] = (short)h;
        vl[i + 4] = (short)f2bf(f - bf2f(h));
    }
}
__device__ __forceinline__ short8 cvt_hi(f32x4 a, f32x4 b) {
    short8 v;
#pragma unroll
    for (int i = 0; i < 4; ++i) { v[i] = (short)f2bf(a[i]); v[i + 4] = (short)f2bf(b[i]); }
    return v;
}

#define MFMA16(A, B, C) __builtin_amdgcn_mfma_f32_16x16x32_bf16(A, B, C, 0, 0, 0)

// ---------------------------------------------------------------- prepass ---
// One launch: blocks [0,XB) split X, [XB,XB+WB) split W, [XB+WB,XB+2*WB) cvt T.
__global__ __launch_bounds__(256) void prepass_all(
    const float* __restrict__ X, const float* __restrict__ W,
    const float* __restrict__ T,
    unsigned short* __restrict__ XH, unsigned short* __restrict__ XL,
    unsigned short* __restrict__ WH, unsigned short* __restrict__ WL,
    unsigned short* __restrict__ TH)
{
    int b = blockIdx.x;
    if (b < XB + WB) {
        const float* src; unsigned short *hi, *lo; int i;
        if (b < XB) { src = X; hi = XH; lo = XL; i = b * 256 + threadIdx.x; }
        else        { src = W; hi = WH; lo = WL; i = (b - XB) * 256 + threadIdx.x; }
        const float* p = src + (size_t)i * 8;
        f32x4 a = *(const f32x4*)p;
        f32x4 c = *(const f32x4*)(p + 4);
        short8 vh, vl;
        cvt_split(a, c, vh, vl);
        *(short8*)&hi[(size_t)i * 8] = vh;
        *(short8*)&lo[(size_t)i * 8] = vl;
    } else {
        int i = (b - XB - WB) * 256 + threadIdx.x;
        const float* p = T + (size_t)i * 8;
        f32x4 a = *(const f32x4*)p;
        f32x4 c = *(const f32x4*)(p + 4);
        *(short8*)&TH[(size_t)i * 8] = cvt_hi(a, c);
    }
}

// ------------------------------------------------------------- main GEMM ----
#define GLL(gp, lp) __builtin_amdgcn_global_load_lds(                      \
        (const __attribute__((address_space(1))) void*)(gp),               \
        (__attribute__((address_space(3))) void*)(lp), 16, 0, 0)

// counted-vmcnt barrier: never drain to 0 in the main loop (T4).
#define VMBAR(N) do {                                                      \
        asm volatile("s_waitcnt vmcnt(" #N ")" ::: "memory");              \
        __builtin_amdgcn_s_barrier();                                      \
        asm volatile("" ::: "memory");                                     \
    } while (0)

__global__ __launch_bounds__(512) void dend_gemm(
    const unsigned short* __restrict__ XH, const unsigned short* __restrict__ XL,
    const unsigned short* __restrict__ WH, const unsigned short* __restrict__ WL,
    const unsigned short* __restrict__ TH, float* __restrict__ O)
{
    // 4-deep pipeline: arrays 0=x_hi 1=x_lo 2=w_hi 3=w_lo 4=t_hi ; 160 KB
    __shared__ __align__(16) short lds[4][5][LDSZ];

    const int tid  = threadIdx.x;
    const int lane = tid & 63;
    const int wv   = tid >> 6;    // 0..7
    const int wm   = wv >> 2;     // 0..1
    const int wn   = wv & 3;      // 0..3

    const int bid     = blockIdx.x;
    const int logical = (bid & 7) * 32 + (bid >> 3);   // XCD-chunked swizzle
    const int hb   = logical >> 5;
    const int nb   = logical & 31;
    const int row0 = nb * BM;
    const int col0 = hb * BH;

    // global_load_lds writes linearly (wave base + lane*16B). Lane l of wave
    // wv lands at LDS row (wv*16 + l/4), slot (l&3). Pre-swizzle the GLOBAL
    // source chunk so the swizzled read offsets below see the right data.
    const int srow = (wv << 4) + (lane >> 2);
    const int sc   = (lane & 3) ^ ((lane >> 3) & 3);
    const size_t xbase = (size_t)(row0 + srow) * K_DIM + sc * 8;
    const size_t wbase = (size_t)(col0 + srow) * K_DIM + sc * 8;

#define STAGE(buf, t) do {                                                 \
        const size_t ko = (size_t)(t) * BK;                                \
        GLL(XH + xbase + ko, &lds[buf][0][wv << 9]);                       \
        GLL(XL + xbase + ko, &lds[buf][1][wv << 9]);                       \
        GLL(WH + wbase + ko, &lds[buf][2][wv << 9]);                       \
        GLL(WL + wbase + ko, &lds[buf][3][wv << 9]);                       \
        GLL(TH + wbase + ko, &lds[buf][4][wv << 9]);                       \
    } while (0)

    // Fragment read offsets (swizzled; layout identical to validated r1/r2)
    const int g = lane >> 4;
    int a_off[4], b_off[2];
#pragma unroll
    for (int mi = 0; mi < 4; ++mi) {
        int r = wm * 64 + mi * 16 + (lane & 15);
        a_off[mi] = r * BK + (g ^ ((r >> 1) & 3)) * 8;
    }
#pragma unroll
    for (int nj = 0; nj < 2; ++nj) {
        int r = wn * 32 + nj * 16 + (lane & 15);
        b_off[nj] = r * BK + (g ^ ((r >> 1) & 3)) * 8;
    }

    const f32x4 zeroc = (f32x4)0.0f;
    f32x4 lin[4][2], num[4][2], den[4][2], win[4][2];
#pragma unroll
    for (int mi = 0; mi < 4; ++mi)
#pragma unroll
        for (int nj = 0; nj < 2; ++nj) {
            lin[mi][nj] = zeroc; num[mi][nj] = zeroc; den[mi][nj] = zeroc;
        }

#define COMPUTE(buf, ZW) do {                                              \
        short8 bwh[2], bwl[2], bth[2];                                     \
        _Pragma("unroll")                                                  \
        for (int nj = 0; nj < 2; ++nj) {                                   \
            bwh[nj] = *(const short8*)&lds[buf][2][b_off[nj]];             \
            bwl[nj] = *(const short8*)&lds[buf][3][b_off[nj]];             \
            bth[nj] = *(const short8*)&lds[buf][4][b_off[nj]];             \
        }                                                                  \
        __builtin_amdgcn_s_setprio(1);                                     \
        _Pragma("unroll")                                                  \
        for (int mi = 0; mi < 4; ++mi) {                                   \
            short8 ah = *(const short8*)&lds[buf][0][a_off[mi]];           \
            short8 al = *(const short8*)&lds[buf][1][a_off[mi]];           \
            _Pragma("unroll")                                              \
            for (int nj = 0; nj < 2; ++nj) {                               \
                lin[mi][nj] = MFMA16(ah, bwh[nj], lin[mi][nj]);            \
                lin[mi][nj] = MFMA16(al, bwh[nj], lin[mi][nj]);            \
                lin[mi][nj] = MFMA16(ah, bwl[nj], lin[mi][nj]);            \
                win[mi][nj] = MFMA16(ah, bth[nj], (ZW) ? zeroc : win[mi][nj]); \
            }                                                              \
        }                                                                  \
        __builtin_amdgcn_s_setprio(0);                                     \
    } while (0)

#define EPILOG() do {                                                      \
        _Pragma("unroll")                                                  \
        for (int mi = 0; mi < 4; ++mi)                                     \
        _Pragma("unroll")                                                  \
        for (int nj = 0; nj < 2; ++nj)                                     \
        _Pragma("unroll")                                                  \
        for (int i = 0; i < 4; ++i) {                                      \
            float d = win[mi][nj][i];                                      \
            float e = __expf(fabsf(d));                                    \
            den[mi][nj][i] += e;                                           \
            num[mi][nj][i] = fmaf(e, d, num[mi][nj][i]);                   \
        }                                                                  \
    } while (0)

    // Prologue: 2 tiles in flight before the first wait.
    STAGE(0, 0);
    STAGE(1, 1);

    // Steady state: stage tile t+2, wait for tile t (10 newer loads stay in
    // flight), barrier, compute. One barrier per K-step; buffer reuse is
    // separated by one barrier (write of t+4 issued only after the barrier
    // certifying all waves finished reading tile t).
#pragma unroll 1
    for (int t = 0; t < 60; t += 4) {
        STAGE(2, t + 2); VMBAR(10); COMPUTE(0, true);
        STAGE(3, t + 3); VMBAR(10); COMPUTE(1, false); EPILOG();
        STAGE(0, t + 4); VMBAR(10); COMPUTE(2, true);
        STAGE(1, t + 5); VMBAR(10); COMPUTE(3, false); EPILOG();
    }
    // Tail: tiles 60..63 (stages 62,63 only), draining vmcnt 10 -> 5 -> 0.
    STAGE(2, 62); VMBAR(10); COMPUTE(0, true);
    STAGE(3, 63); VMBAR(10); COMPUTE(1, false); EPILOG();
    VMBAR(5);  COMPUTE(2, true);
    VMBAR(0);  COMPUTE(3, false); EPILOG();

    // Final epilogue: g = num/den, silu, multiply, store.
#pragma unroll
    for (int mi = 0; mi < 4; ++mi)
#pragma unroll
        for (int nj = 0; nj < 2; ++nj)
#pragma unroll
            for (int i = 0; i < 4; ++i) {
                float gg   = num[mi][nj][i] / den[mi][nj][i];
                float gate = gg / (1.0f + __expf(-gg));
                float val  = gate * lin[mi][nj][i];
                int r = row0 + wm * 64 + mi * 16 + (lane >> 4) * 4 + i;
                int c = col0 + wn * 32 + nj * 16 + (lane & 15);
                O[(size_t)r * H_DIM + c] = val;
            }
#undef STAGE
#undef COMPUTE
#undef EPILOG
}

// ------------------------------------------------- fallback (round-1 path) --
__global__ __launch_bounds__(512) void dend_fused_v0(
    const float* __restrict__ X, const float* __restrict__ T,
    const float* __restrict__ W, float* __restrict__ O)
{
    __shared__ __align__(16) short lds[2][5][LDSZ];

    const int tid  = threadIdx.x;
    const int lane = tid & 63;
    const int wv   = tid >> 6;
    const int wm   = wv >> 2;
    const int wn   = wv & 3;

    const int bid     = blockIdx.x;
    const int logical = (bid & 7) * 32 + (bid >> 3);
    const int hb   = logical >> 5;
    const int nb   = logical & 31;
    const int row0 = nb * BM;
    const int col0 = hb * BH;

    const int srow  = tid >> 2;
    const int schn  = tid & 3;
    const int sslot = schn ^ ((srow >> 1) & 3);
    const int swoff = srow * BK + sslot * 8;

    const float* gx = X + (size_t)(row0 + srow) * K_DIM + schn * 8;
    const float* gw = W + (size_t)(col0 + srow) * K_DIM + schn * 8;
    const float* gt = T + (size_t)(col0 + srow) * K_DIM + schn * 8;

    const int g = lane >> 4;
    int a_off[4], b_off[2];
#pragma unroll
    for (int mi = 0; mi < 4; ++mi) {
        int r = wm * 64 + mi * 16 + (lane & 15);
        a_off[mi] = r * BK + (g ^ ((r >> 1) & 3)) * 8;
    }
#pragma unroll
    for (int nj = 0; nj < 2; ++nj) {
        int r = wn * 32 + nj * 16 + (lane & 15);
        b_off[nj] = r * BK + (g ^ ((r >> 1) & 3)) * 8;
    }

    const f32x4 zeroc = (f32x4)0.0f;
    f32x4 lin[4][2], num[4][2], den[4][2], win[4][2];
#pragma unroll
    for (int mi = 0; mi < 4; ++mi)
#pragma unroll
        for (int nj = 0; nj < 2; ++nj) {
            lin[mi][nj] = zeroc; num[mi][nj] = zeroc; den[mi][nj] = zeroc;
        }

    f32x4 rx0, rx1, rw0, rw1, rt0, rt1;

#define LOADS(t) do {                                                   \
        const float* px = gx + (size_t)(t) * BK;                        \
        const float* pw = gw + (size_t)(t) * BK;                        \
        const float* pt = gt + (size_t)(t) * BK;                        \
        rx0 = *(const f32x4*)(px); rx1 = *(const f32x4*)(px + 4);       \
        rw0 = *(const f32x4*)(pw); rw1 = *(const f32x4*)(pw + 4);       \
        rt0 = *(const f32x4*)(pt); rt1 = *(const f32x4*)(pt + 4);       \
    } while (0)

#define WRITE(buf) do {                                                 \
        short8 vh, vl;                                                  \
        cvt_split(rx0, rx1, vh, vl);                                    \
        *(short8*)&lds[buf][0][swoff] = vh;                             \
        *(short8*)&lds[buf][1][swoff] = vl;                             \
        cvt_split(rw0, rw1, vh, vl);                                    \
        *(short8*)&lds[buf][2][swoff] = vh;                             \
        *(short8*)&lds[buf][3][swoff] = vl;                             \
        *(short8*)&lds[buf][4][swoff] = cvt_hi(rt0, rt1);               \
    } while (0)

#define COMPUTE(buf, ZW) do {                                           \
        short8 bwh[2], bwl[2], bth[2];                                  \
        _Pragma("unroll")                                               \
        for (int nj = 0; nj < 2; ++nj) {                                \
            bwh[nj] = *(const short8*)&lds[buf][2][b_off[nj]];          \
            bwl[nj] = *(const short8*)&lds[buf][3][b_off[nj]];          \
            bth[nj] = *(const short8*)&lds[buf][4][b_off[nj]];          \
        }                                                               \
        _Pragma("unroll")                                               \
        for (int mi = 0; mi < 4; ++mi) {                                \
            short8 ah = *(const short8*)&lds[buf][0][a_off[mi]];        \
            short8 al = *(const short8*)&lds[buf][1][a_off[mi]];        \
            _Pragma("unroll")                                           \
            for (int nj = 0; nj < 2; ++nj) {                            \
                lin[mi][nj] = MFMA16(ah, bwh[nj], lin[mi][nj]);         \
                lin[mi][nj] = MFMA16(al, bwh[nj], lin[mi][nj]);         \
                lin[mi][nj] = MFMA16(ah, bwl[nj], lin[mi][nj]);         \
                win[mi][nj] = MFMA16(ah, bth[nj], (ZW) ? zeroc : win[mi][nj]); \
            }                                                           \
        }                                                               \
    } while (0)

#define EPILOG() do {                                                   \
        _Pragma("unroll")                                               \
        for (int mi = 0; mi < 4; ++mi)                                  \
        _Pragma("unroll")                                               \
        for (int nj = 0; nj < 2; ++nj)                                  \
        _Pragma("unroll")                                               \
        for (int i = 0; i < 4; ++i) {                                   \
            float d = win[mi][nj][i];                                   \
            float e = __expf(fabsf(d));                                 \
            den[mi][nj][i] += e;                                        \
            num[mi][nj][i] = fmaf(e, d, num[mi][nj][i]);                \
        }                                                               \
    } while (0)

    LOADS(0);
    WRITE(0);
    __syncthreads();

#pragma unroll 1
    for (int w = 0; w < 32; ++w) {
        const int t0 = 2 * w;
        LOADS(t0 + 1);
        COMPUTE(0, true);
        __syncthreads();
        WRITE(1);
        __syncthreads();
        const bool more = (w < 31);
        if (more) LOADS(t0 + 2);
        COMPUTE(1, false);
        EPILOG();
        __syncthreads();
        if (more) WRITE(0);
        __syncthreads();
    }

#pragma unroll
    for (int mi = 0; mi < 4; ++mi)
#pragma unroll
        for (int nj = 0; nj < 2; ++nj)
#pragma unroll
            for (int i = 0; i < 4; ++i) {
                float gg   = num[mi][nj][i] / den[mi][nj][i];
                float gate = gg / (1.0f + __expf(-gg));
                float val  = gate * lin[mi][nj][i];
                int r = row0 + wm * 64 + mi * 16 + (lane >> 4) * 4 + i;
                int c = col0 + wn * 32 + nj * 16 + (lane & 15);
                O[(size_t)r * H_DIM + c] = val;
            }
#undef LOADS
#undef WRITE
#undef COMPUTE
#undef EPILOG
}

extern "C" void kernel_launch(void* const* d_in, const int* in_sizes, int n_in,
                              void* d_out, int out_size, void* d_ws, size_t ws_size,
                              hipStream_t stream) {
    const float* X = (const float*)d_in[0];   // x [4096,2048]
    const float* T = (const float*)d_in[1];   // template_flat [1024,2048]
    const float* W = (const float*)d_in[2];   // weights [1024,2048]
    float* O = (float*)d_out;                 // [4096,1024]
    (void)in_sizes; (void)n_in; (void)out_size;

    if (ws_size >= WS_NEED) {
        unsigned short* XHp = (unsigned short*)d_ws;
        unsigned short* XLp = XHp + X_ELEMS;
        unsigned short* WHp = XLp + X_ELEMS;
        unsigned short* WLp = WHp + W_ELEMS;
        unsigned short* THp = WLp + W_ELEMS;
        prepass_all<<<XB + 2 * WB, 256, 0, stream>>>(X, W, T, XHp, XLp, WHp, WLp, THp);
        dend_gemm<<<256, 512, 0, stream>>>(XHp, XLp, WHp, WLp, THp, O);
    } else {
        dend_fused_v0<<<256, 512, 0, stream>>>(X, T, W, O);
    }
}

// Round 4
// 112.320 us; speedup vs baseline: 1.6731x; 1.6731x over previous
//
#include <hip/hip_runtime.h>
#include <hip/hip_bf16.h>

// DendriticLayerSiLU: out = silu(softmax-gated template proj) * (x @ W^T)
// N=4096 tokens, K=2048, H=1024, 32 windows of 64.
// Round 4: round-2 structure (validated), tile 64x128 -> 64 KB LDS, 2 blocks/CU.
// acc halved to 64 regs; __launch_bounds__(512,4) to guarantee co-residency.

typedef __attribute__((ext_vector_type(8))) short short8;
typedef __attribute__((ext_vector_type(4))) float f32x4;

#define N_TOK 4096
#define K_DIM 2048
#define H_DIM 1024
#define BM 64
#define BH 128
#define BK 32

#define X_ELEMS (N_TOK * K_DIM)   // 8388608
#define W_ELEMS (H_DIM * K_DIM)   // 2097152
#define WS_NEED ((size_t)(2 * X_ELEMS + 3 * W_ELEMS) * 2)  // 46,137,344 B

#define XB (X_ELEMS / 8 / 256)    // 4096 prepass blocks for X
#define WB (W_ELEMS / 8 / 256)    // 1024 for W, 1024 for T

__device__ __forceinline__ unsigned short f2bf(float f) {
    unsigned int u = __float_as_uint(f);
    u += 0x7FFFu + ((u >> 16) & 1u);    // round-to-nearest-even
    return (unsigned short)(u >> 16);
}
__device__ __forceinline__ float bf2f(unsigned short h) {
    return __uint_as_float(((unsigned int)h) << 16);
}

__device__ __forceinline__ void cvt_split(f32x4 a, f32x4 b, short8& vh, short8& vl) {
#pragma unroll
    for (int i = 0; i < 4; ++i) {
        float f = a[i];
        unsigned short h = f2bf(f);
        vh[i] = (short)h;
        vl[i] = (short)f2bf(f - bf2f(h));
    }
#pragma unroll
    for (int i = 0; i < 4; ++i) {
        float f = b[i];
        unsigned short h = f2bf(f);
        vh[i + 4] = (short)h;
        vl[i + 4] = (short)f2bf(f - bf2f(h));
    }
}
__device__ __forceinline__ short8 cvt_hi(f32x4 a, f32x4 b) {
    short8 v;
#pragma unroll
    for (int i = 0; i < 4; ++i) { v[i] = (short)f2bf(a[i]); v[i + 4] = (short)f2bf(b[i]); }
    return v;
}

#define MFMA16(A, B, C) __builtin_amdgcn_mfma_f32_16x16x32_bf16(A, B, C, 0, 0, 0)

// ---------------------------------------------------------------- prepass ---
__global__ __launch_bounds__(256) void prepass_all(
    const float* __restrict__ X, const float* __restrict__ W,
    const float* __restrict__ T,
    unsigned short* __restrict__ XH, unsigned short* __restrict__ XL,
    unsigned short* __restrict__ WH, unsigned short* __restrict__ WL,
    unsigned short* __restrict__ TH)
{
    int b = blockIdx.x;
    if (b < XB + WB) {
        const float* src; unsigned short *hi, *lo; int i;
        if (b < XB) { src = X; hi = XH; lo = XL; i = b * 256 + threadIdx.x; }
        else        { src = W; hi = WH; lo = WL; i = (b - XB) * 256 + threadIdx.x; }
        const float* p = src + (size_t)i * 8;
        f32x4 a = *(const f32x4*)p;
        f32x4 c = *(const f32x4*)(p + 4);
        short8 vh, vl;
        cvt_split(a, c, vh, vl);
        *(short8*)&hi[(size_t)i * 8] = vh;
        *(short8*)&lo[(size_t)i * 8] = vl;
    } else {
        int i = (b - XB - WB) * 256 + threadIdx.x;
        const float* p = T + (size_t)i * 8;
        f32x4 a = *(const f32x4*)p;
        f32x4 c = *(const f32x4*)(p + 4);
        *(short8*)&TH[(size_t)i * 8] = cvt_hi(a, c);
    }
}

// ------------------------------------------------------------- main GEMM ----
#define GLL(gp, lp) __builtin_amdgcn_global_load_lds(                      \
        (const __attribute__((address_space(1))) void*)(gp),               \
        (__attribute__((address_space(3))) void*)(lp), 16, 0, 0)

__global__ __launch_bounds__(512, 4) void dend_gemm(
    const unsigned short* __restrict__ XH, const unsigned short* __restrict__ XL,
    const unsigned short* __restrict__ WH, const unsigned short* __restrict__ WL,
    const unsigned short* __restrict__ TH, float* __restrict__ O)
{
    // double-buffered: X 2 arrays [64][32], W/T 3 arrays [128][32] = 64 KB
    __shared__ __align__(16) short ldsx[2][2][BM * BK];   // 16 KB
    __shared__ __align__(16) short ldsw[2][3][BH * BK];   // 48 KB

    const int tid  = threadIdx.x;
    const int lane = tid & 63;
    const int wv   = tid >> 6;    // 0..7
    const int wm   = wv >> 2;     // 0..1  (32 token-rows each)
    const int wn   = wv & 3;      // 0..3  (32 units each)

    // grid 512 = 64 row-blocks x 8 col-panels; XCD-chunked: XCD k owns panel k
    const int bid     = blockIdx.x;
    const int logical = (bid & 7) * 64 + (bid >> 3);
    const int hb   = logical >> 6;   // 0..7
    const int nb   = logical & 63;   // 0..63
    const int row0 = nb * BM;
    const int col0 = hb * BH;

    // Staging: GLL writes linearly (wave base + lane*16B); lane l covers row
    // (lane>>2) of a 16-row stripe, slot (l&3). Pre-swizzle the GLOBAL chunk:
    // slot s of row r must hold chunk s ^ ((r>>1)&3)  (validated r1/r2 layout).
    const int sc   = (lane & 3) ^ ((lane >> 3) & 3);
    // X arrays: 64 rows = 4 waves each. waves 0-3 -> X_hi, waves 4-7 -> X_lo.
    const unsigned short* xsrc = (wv < 4) ? XH : XL;
    const int xarr = wv >> 2;                       // 0=hi 1=lo
    const int xrow = (wv & 3) * 16 + (lane >> 2);   // 0..63
    // W/T arrays: 128 rows = all 8 waves.
    const int wrow = wv * 16 + (lane >> 2);         // 0..127
    const size_t xbase = (size_t)(row0 + xrow) * K_DIM + sc * 8;
    const size_t wbase = (size_t)(col0 + wrow) * K_DIM + sc * 8;

#define STAGE(buf, t) do {                                                 \
        const size_t ko = (size_t)(t) * BK;                                \
        GLL(xsrc + xbase + ko, &ldsx[buf][xarr][(wv & 3) << 9]);           \
        GLL(WH + wbase + ko, &ldsw[buf][0][wv << 9]);                      \
        GLL(WL + wbase + ko, &ldsw[buf][1][wv << 9]);                      \
        GLL(TH + wbase + ko, &ldsw[buf][2][wv << 9]);                      \
    } while (0)

    // Fragment read offsets (same swizzle formula as validated rounds)
    const int g = lane >> 4;
    int a_off[2], b_off[2];
#pragma unroll
    for (int mi = 0; mi < 2; ++mi) {
        int r = wm * 32 + mi * 16 + (lane & 15);    // 0..63
        a_off[mi] = r * BK + (g ^ ((r >> 1) & 3)) * 8;
    }
#pragma unroll
    for (int nj = 0; nj < 2; ++nj) {
        int r = wn * 32 + nj * 16 + (lane & 15);    // 0..127
        b_off[nj] = r * BK + (g ^ ((r >> 1) & 3)) * 8;
    }

    const f32x4 zeroc = (f32x4)0.0f;
    f32x4 lin[2][2], num[2][2], den[2][2], win[2][2];
#pragma unroll
    for (int mi = 0; mi < 2; ++mi)
#pragma unroll
        for (int nj = 0; nj < 2; ++nj) {
            lin[mi][nj] = zeroc; num[mi][nj] = zeroc; den[mi][nj] = zeroc;
        }

#define COMPUTE(buf, ZW) do {                                              \
        short8 bwh[2], bwl[2], bth[2];                                     \
        _Pragma("unroll")                                                  \
        for (int nj = 0; nj < 2; ++nj) {                                   \
            bwh[nj] = *(const short8*)&ldsw[buf][0][b_off[nj]];            \
            bwl[nj] = *(const short8*)&ldsw[buf][1][b_off[nj]];            \
            bth[nj] = *(const short8*)&ldsw[buf][2][b_off[nj]];            \
        }                                                                  \
        _Pragma("unroll")                                                  \
        for (int mi = 0; mi < 2; ++mi) {                                   \
            short8 ah = *(const short8*)&ldsx[buf][0][a_off[mi]];          \
            short8 al = *(const short8*)&ldsx[buf][1][a_off[mi]];          \
            _Pragma("unroll")                                              \
            for (int nj = 0; nj < 2; ++nj) {                               \
                lin[mi][nj] = MFMA16(ah, bwh[nj], lin[mi][nj]);            \
                lin[mi][nj] = MFMA16(al, bwh[nj], lin[mi][nj]);            \
                lin[mi][nj] = MFMA16(ah, bwl[nj], lin[mi][nj]);            \
                win[mi][nj] = MFMA16(ah, bth[nj], (ZW) ? zeroc : win[mi][nj]); \
            }                                                              \
        }                                                                  \
    } while (0)

#define EPILOG() do {                                                      \
        _Pragma("unroll")                                                  \
        for (int mi = 0; mi < 2; ++mi)                                     \
        _Pragma("unroll")                                                  \
        for (int nj = 0; nj < 2; ++nj)                                     \
        _Pragma("unroll")                                                  \
        for (int i = 0; i < 4; ++i) {                                      \
            float d = win[mi][nj][i];                                      \
            float e = __expf(fabsf(d));                                    \
            den[mi][nj][i] += e;                                           \
            num[mi][nj][i] = fmaf(e, d, num[mi][nj][i]);                   \
        }                                                                  \
    } while (0)

    STAGE(0, 0);
    __syncthreads();

#pragma unroll 1
    for (int w = 0; w < 32; ++w) {
        const int t0 = 2 * w;
        STAGE(1, t0 + 1);
        COMPUTE(0, true);
        __syncthreads();
        if (t0 + 2 < 64) STAGE(0, t0 + 2);
        COMPUTE(1, false);
        EPILOG();
        __syncthreads();
    }

    // Final epilogue: g = num/den, silu, multiply, store.
#pragma unroll
    for (int mi = 0; mi < 2; ++mi)
#pragma unroll
        for (int nj = 0; nj < 2; ++nj)
#pragma unroll
            for (int i = 0; i < 4; ++i) {
                float gg   = num[mi][nj][i] / den[mi][nj][i];
                float gate = gg / (1.0f + __expf(-gg));
                float val  = gate * lin[mi][nj][i];
                int r = row0 + wm * 32 + mi * 16 + (lane >> 4) * 4 + i;
                int c = col0 + wn * 32 + nj * 16 + (lane & 15);
                O[(size_t)r * H_DIM + c] = val;
            }
#undef STAGE
#undef COMPUTE
#undef EPILOG
}

// ------------------------------------------------- fallback (round-1 path) --
__global__ __launch_bounds__(512) void dend_fused_v0(
    const float* __restrict__ X, const float* __restrict__ T,
    const float* __restrict__ W, float* __restrict__ O)
{
    __shared__ __align__(16) short lds[2][5][128 * BK];

    const int tid  = threadIdx.x;
    const int lane = tid & 63;
    const int wv   = tid >> 6;
    const int wm   = wv >> 2;
    const int wn   = wv & 3;

    const int bid     = blockIdx.x;
    const int logical = (bid & 7) * 32 + (bid >> 3);
    const int hb   = logical >> 5;
    const int nb   = logical & 31;
    const int row0 = nb * 128;
    const int col0 = hb * 128;

    const int srow  = tid >> 2;
    const int schn  = tid & 3;
    const int sslot = schn ^ ((srow >> 1) & 3);
    const int swoff = srow * BK + sslot * 8;

    const float* gx = X + (size_t)(row0 + srow) * K_DIM + schn * 8;
    const float* gw = W + (size_t)(col0 + srow) * K_DIM + schn * 8;
    const float* gt = T + (size_t)(col0 + srow) * K_DIM + schn * 8;

    const int g = lane >> 4;
    int a_off[4], b_off[2];
#pragma unroll
    for (int mi = 0; mi < 4; ++mi) {
        int r = wm * 64 + mi * 16 + (lane & 15);
        a_off[mi] = r * BK + (g ^ ((r >> 1) & 3)) * 8;
    }
#pragma unroll
    for (int nj = 0; nj < 2; ++nj) {
        int r = wn * 32 + nj * 16 + (lane & 15);
        b_off[nj] = r * BK + (g ^ ((r >> 1) & 3)) * 8;
    }

    const f32x4 zeroc = (f32x4)0.0f;
    f32x4 lin[4][2], num[4][2], den[4][2], win[4][2];
#pragma unroll
    for (int mi = 0; mi < 4; ++mi)
#pragma unroll
        for (int nj = 0; nj < 2; ++nj) {
            lin[mi][nj] = zeroc; num[mi][nj] = zeroc; den[mi][nj] = zeroc;
        }

    f32x4 rx0, rx1, rw0, rw1, rt0, rt1;

#define LOADS(t) do {                                                   \
        const float* px = gx + (size_t)(t) * BK;                        \
        const float* pw = gw + (size_t)(t) * BK;                        \
        const float* pt = gt + (size_t)(t) * BK;                        \
        rx0 = *(const f32x4*)(px); rx1 = *(const f32x4*)(px + 4);       \
        rw0 = *(const f32x4*)(pw); rw1 = *(const f32x4*)(pw + 4);       \
        rt0 = *(const f32x4*)(pt); rt1 = *(const f32x4*)(pt + 4);       \
    } while (0)

#define WRITE(buf) do {                                                 \
        short8 vh, vl;                                                  \
        cvt_split(rx0, rx1, vh, vl);                                    \
        *(short8*)&lds[buf][0][swoff] = vh;                             \
        *(short8*)&lds[buf][1][swoff] = vl;                             \
        cvt_split(rw0, rw1, vh, vl);                                    \
        *(short8*)&lds[buf][2][swoff] = vh;                             \
        *(short8*)&lds[buf][3][swoff] = vl;                             \
        *(short8*)&lds[buf][4][swoff] = cvt_hi(rt0, rt1);               \
    } while (0)

#define COMPUTE(buf, ZW) do {                                           \
        short8 bwh[2], bwl[2], bth[2];                                  \
        _Pragma("unroll")                                               \
        for (int nj = 0; nj < 2; ++nj) {                                \
            bwh[nj] = *(const short8*)&lds[buf][2][b_off[nj]];          \
            bwl[nj] = *(const short8*)&lds[buf][3][b_off[nj]];          \
            bth[nj] = *(const short8*)&lds[buf][4][b_off[nj]];          \
        }                                                               \
        _Pragma("unroll")                                               \
        for (int mi = 0; mi < 4; ++mi) {                                \
            short8 ah = *(const short8*)&lds[buf][0][a_off[mi]];        \
            short8 al = *(const short8*)&lds[buf][1][a_off[mi]];        \
            _Pragma("unroll")                                           \
            for (int nj = 0; nj < 2; ++nj) {                            \
                lin[mi][nj] = MFMA16(ah, bwh[nj], lin[mi][nj]);         \
                lin[mi][nj] = MFMA16(al, bwh[nj], lin[mi][nj]);         \
                lin[mi][nj] = MFMA16(ah, bwl[nj], lin[mi][nj]);         \
                win[mi][nj] = MFMA16(ah, bth[nj], (ZW) ? zeroc : win[mi][nj]); \
            }                                                           \
        }                                                               \
    } while (0)

#define EPILOG() do {                                                   \
        _Pragma("unroll")                                               \
        for (int mi = 0; mi < 4; ++mi)                                  \
        _Pragma("unroll")                                               \
        for (int nj = 0; nj < 2; ++nj)                                  \
        _Pragma("unroll")                                               \
        for (int i = 0; i < 4; ++i) {                                   \
            float d = win[mi][nj][i];                                   \
            float e = __expf(fabsf(d));                                 \
            den[mi][nj][i] += e;                                        \
            num[mi][nj][i] = fmaf(e, d, num[mi][nj][i]);                \
        }                                                               \
    } while (0)

    LOADS(0);
    WRITE(0);
    __syncthreads();

#pragma unroll 1
    for (int w = 0; w < 32; ++w) {
        const int t0 = 2 * w;
        LOADS(t0 + 1);
        COMPUTE(0, true);
        __syncthreads();
        WRITE(1);
        __syncthreads();
        const bool more = (w < 31);
        if (more) LOADS(t0 + 2);
        COMPUTE(1, false);
        EPILOG();
        __syncthreads();
        if (more) WRITE(0);
        __syncthreads();
    }

#pragma unroll
    for (int mi = 0; mi < 4; ++mi)
#pragma unroll
        for (int nj = 0; nj < 2; ++nj)
#pragma unroll
            for (int i = 0; i < 4; ++i) {
                float gg   = num[mi][nj][i] / den[mi][nj][i];
                float gate = gg / (1.0f + __expf(-gg));
                float val  = gate * lin[mi][nj][i];
                int r = row0 + wm * 64 + mi * 16 + (lane >> 4) * 4 + i;
                int c = col0 + wn * 32 + nj * 16 + (lane & 15);
                O[(size_t)r * H_DIM + c] = val;
            }
#undef LOADS
#undef WRITE
#undef COMPUTE
#undef EPILOG
}

extern "C" void kernel_launch(void* const* d_in, const int* in_sizes, int n_in,
                              void* d_out, int out_size, void* d_ws, size_t ws_size,
                              hipStream_t stream) {
    const float* X = (const float*)d_in[0];   // x [4096,2048]
    const float* T = (const float*)d_in[1];   // template_flat [1024,2048]
    const float* W = (const float*)d_in[2];   // weights [1024,2048]
    float* O = (float*)d_out;                 // [4096,1024]
    (void)in_sizes; (void)n_in; (void)out_size;

    if (ws_size >= WS_NEED) {
        unsigned short* XHp = (unsigned short*)d_ws;
        unsigned short* XLp = XHp + X_ELEMS;
        unsigned short* WHp = XLp + X_ELEMS;
        unsigned short* WLp = WHp + W_ELEMS;
        unsigned short* THp = WLp + W_ELEMS;
        prepass_all<<<XB + 2 * WB, 256, 0, stream>>>(X, W, T, XHp, XLp, WHp, WLp, THp);
        dend_gemm<<<512, 512, 0, stream>>>(XHp, XLp, WHp, WLp, THp, O);
    } else {
        dend_fused_v0<<<256, 512, 0, stream>>>(X, T, W, O);
    }
}